// Round 1
// baseline (62.472 us; speedup 1.0000x reference)
//
#include <hip/hip_runtime.h>
#include <math.h>

#define NNODE 512
#define NBATCH 4
#define NFEAT 12
#define QKD 128
#define NVD 128
#define EVD 32
#define CATD 160          // NVD + EVD
#define TRD 256
#define NCLS 5
#define TI 8              // query rows per block in attn kernel
#define NROWS 2048        // NBATCH * NNODE
#define EPSV 1e-5f

// ---------------------------------------------------------------------------
// Kernel 1: Q, K, NV projections (2048 rows x 12 -> 128 each). Also zeroes
// the BN-stats accumulator (block 0) so no separate memset node is needed.
// ---------------------------------------------------------------------------
__global__ __launch_bounds__(128) void qkv_kernel(
    const float* __restrict__ nodes,
    const float* __restrict__ Wq, const float* __restrict__ bq,
    const float* __restrict__ Wk, const float* __restrict__ bk,
    const float* __restrict__ Wnv, const float* __restrict__ bnv,
    float* __restrict__ Q, float* __restrict__ K, float* __restrict__ NV,
    float* __restrict__ stats) {
  const int row = blockIdx.x;      // 0..2047
  const int d   = threadIdx.x;     // 0..127
  if (row == 0) {                  // zero 512-float stats region (sum|sqsum)
    stats[d] = 0.f; stats[d + 128] = 0.f; stats[d + 256] = 0.f; stats[d + 384] = 0.f;
  }
  __shared__ float sn[NFEAT];
  if (d < NFEAT) sn[d] = nodes[row * NFEAT + d];
  __syncthreads();
  float aq = bq[d], ak = bk[d], av = bnv[d];
#pragma unroll
  for (int k = 0; k < NFEAT; ++k) {
    const float n = sn[k];
    aq = fmaf(n, Wq[d * NFEAT + k], aq);
    ak = fmaf(n, Wk[d * NFEAT + k], ak);
    av = fmaf(n, Wnv[d * NFEAT + k], av);
  }
  Q[row * QKD + d]  = aq;
  K[row * QKD + d]  = ak;
  NV[row * NVD + d] = av;
}

// ---------------------------------------------------------------------------
// Kernel 2: per block = 8 query rows of one batch.
//   phase1: scores QK^T * coeff / (dist+1), mask -> -inf      (thread = j)
//   phase2: softmax per row (1 wave per row), + sum_w, sum_we
//   phase3: node_part = w @ NV (j-split over 4 groups, LDS combine) -> tanh
//   phase4: vals = tanh_cat @ Wt^T + bt (Wt staged in LDS, padded stride 33)
//           + atomic BN partial sums
// ---------------------------------------------------------------------------
__global__ __launch_bounds__(512) void attn_kernel(
    const float* __restrict__ Q, const float* __restrict__ K,
    const float* __restrict__ NV,
    const float* __restrict__ edges, const float* __restrict__ dist,
    const int* __restrict__ mask,
    const float* __restrict__ Wev, const float* __restrict__ bev,
    const float* __restrict__ Wt, const float* __restrict__ bt,
    float* __restrict__ vals, float* __restrict__ stats) {
  __shared__ __align__(16) float sQ[TI][QKD];     // 4 KB
  __shared__ __align__(16) float sS[TI][NNODE];   // 16 KB (scores->w->partials)
  __shared__ __align__(16) float sT[TI][CATD];    // 5 KB  (tanh concat)
  __shared__ float sWt[TRD * 33];                 // 33.8 KB (padded Wt tile)
  __shared__ float sSW[TI], sSE[TI];

  const int tid = threadIdx.x;
  const int bid = blockIdx.x;          // 0..255
  const int b   = bid >> 6;            // 64 blocks per batch
  const int i0  = (bid & 63) * TI;
  const int rowbase = b * NNODE + i0;

  for (int idx = tid; idx < TI * QKD; idx += 512)
    sQ[idx >> 7][idx & 127] = Q[(size_t)(rowbase + (idx >> 7)) * QKD + (idx & 127)];
  __syncthreads();

  // ---- phase 1: scores -------------------------------------------------
  {
    const int j = tid;  // 0..511
    const float4* K4 = (const float4*)(K + (size_t)(b * NNODE + j) * QKD);
    float acc[TI];
#pragma unroll
    for (int ii = 0; ii < TI; ++ii) acc[ii] = 0.f;
#pragma unroll 4
    for (int kk = 0; kk < QKD / 4; ++kk) {
      const float4 kv = K4[kk];
#pragma unroll
      for (int ii = 0; ii < TI; ++ii) {
        const float4 qv = ((const float4*)sQ[ii])[kk];
        acc[ii] += qv.x * kv.x + qv.y * kv.y + qv.z * kv.z + qv.w * kv.w;
      }
    }
    const float coeff = 0.0883883476483184f;  // 1/sqrt(128)
#pragma unroll
    for (int ii = 0; ii < TI; ++ii) {
      const size_t off = (size_t)(rowbase + ii) * NNODE + j;
      float s = acc[ii] * coeff / (dist[off] + 1.0f);
      if (mask[off] != 0) s = -__builtin_inff();
      sS[ii][j] = s;
    }
  }
  __syncthreads();

  // ---- phase 2: softmax (wave per row) + row sums ----------------------
  {
    const int i    = tid >> 6;   // 8 waves = 8 rows
    const int lane = tid & 63;
    float v[NNODE / 64];
    float m = -__builtin_inff();
#pragma unroll
    for (int t = 0; t < NNODE / 64; ++t) {
      v[t] = sS[i][lane + 64 * t];
      m = fmaxf(m, v[t]);
    }
#pragma unroll
    for (int s = 1; s < 64; s <<= 1) m = fmaxf(m, __shfl_xor(m, s, 64));
    float sum = 0.f;
    if (m > -__builtin_inff()) {          // wave-uniform branch
#pragma unroll
      for (int t = 0; t < NNODE / 64; ++t) { v[t] = __expf(v[t] - m); sum += v[t]; }
    } else {                              // fully-masked row -> zero weights
#pragma unroll
      for (int t = 0; t < NNODE / 64; ++t) v[t] = 0.f;
    }
#pragma unroll
    for (int s = 1; s < 64; s <<= 1) sum += __shfl_xor(sum, s, 64);
    const float inv = (sum > 0.f) ? 1.f / sum : 0.f;
    const float* erow = edges + (size_t)(rowbase + i) * NNODE;
    float sw = 0.f, se = 0.f;
#pragma unroll
    for (int t = 0; t < NNODE / 64; ++t) {
      const float w = v[t] * inv;
      sS[i][lane + 64 * t] = w;
      sw += w;
      se = fmaf(w, erow[lane + 64 * t], se);
    }
#pragma unroll
    for (int s = 1; s < 64; s <<= 1) {
      sw += __shfl_xor(sw, s, 64);
      se += __shfl_xor(se, s, 64);
    }
    if (lane == 0) { sSW[i] = sw; sSE[i] = se; }
  }
  __syncthreads();

  // ---- phase 3: node_part = w @ NV, j-split over 4 thread groups -------
  {
    const int d = tid & 127;
    const int g = tid >> 7;        // 0..3, each group owns 128 j's
    float acc[TI];
#pragma unroll
    for (int ii = 0; ii < TI; ++ii) acc[ii] = 0.f;
    const float* __restrict__ NVb = NV + (size_t)b * NNODE * NVD + d;
    const int j0 = g * 128;
    for (int jj = 0; jj < 128; ++jj) {
      const int j = j0 + jj;
      const float nv = NVb[(size_t)j * NVD];
#pragma unroll
      for (int ii = 0; ii < TI; ++ii) acc[ii] = fmaf(sS[ii][j], nv, acc[ii]);
    }
    __syncthreads();               // everyone done reading w from sS
    float* part = &sS[0][0];       // reuse as [4][TI][128] partials
#pragma unroll
    for (int ii = 0; ii < TI; ++ii) part[(g * TI + ii) * 128 + d] = acc[ii];
  }
  __syncthreads();
  {
    const float* part = &sS[0][0];
    for (int idx = tid; idx < TI * NVD; idx += 512) {
      const int ii = idx >> 7, d = idx & 127;
      const float v = part[(0 * TI + ii) * 128 + d] + part[(1 * TI + ii) * 128 + d]
                    + part[(2 * TI + ii) * 128 + d] + part[(3 * TI + ii) * 128 + d];
      sT[ii][d] = tanhf(v);
    }
    if (tid < TI * EVD) {          // edge part: Wev*se + bev*sw (EF==1 collapse)
      const int ii = tid >> 5, de = tid & 31;
      sT[ii][NVD + de] = tanhf(fmaf(Wev[de], sSE[ii], bev[de] * sSW[ii]));
    }
  }
  __syncthreads();

  // ---- phase 4: vals = tanh_cat @ Wt^T + bt, BN stats ------------------
  {
    const int o = tid & 255;
    const int h = tid >> 8;        // 0..1 -> rows h*4 .. h*4+3
    float acc[4] = {0.f, 0.f, 0.f, 0.f};
    for (int kc = 0; kc < CATD; kc += 32) {
      __syncthreads();             // protect sWt from previous tile's readers
      for (int idx = tid; idx < TRD * 32; idx += 512) {
        const int oo = idx >> 5, kk = idx & 31;
        sWt[oo * 33 + kk] = Wt[oo * CATD + kc + kk];   // padded: stride 33
      }
      __syncthreads();
#pragma unroll
      for (int kk = 0; kk < 32; ++kk) {
        const float w = sWt[o * 33 + kk];
#pragma unroll
        for (int q = 0; q < 4; ++q)
          acc[q] = fmaf(sT[h * 4 + q][kc + kk], w, acc[q]);
      }
    }
    const float bto = bt[o];
    float s1 = 0.f, s2 = 0.f;
#pragma unroll
    for (int q = 0; q < 4; ++q) {
      const float v2 = acc[q] + bto;
      vals[(size_t)(rowbase + h * 4 + q) * TRD + o] = v2;
      s1 += v2;
      s2 = fmaf(v2, v2, s2);
    }
    atomicAdd(&stats[o], s1);
    atomicAdd(&stats[TRD + o], s2);
  }
}

// ---------------------------------------------------------------------------
// Kernel 3: fold BN (biased batch stats) + gamma/beta into classifier:
//   Weff[c][o] = Wc[c][o]*gamma[o]*inv[o]
//   beff[c]    = bc[c] + sum_o (beta[o]-mu[o]*gamma[o]*inv[o])*Wc[c][o]
// ---------------------------------------------------------------------------
__global__ __launch_bounds__(256) void bnprep_kernel(
    const float* __restrict__ stats,
    const float* __restrict__ gamma, const float* __restrict__ beta,
    const float* __restrict__ Wc, const float* __restrict__ bc,
    float* __restrict__ Weff, float* __restrict__ beff) {
  const int o = threadIdx.x;       // 0..255
  const float invN = 1.0f / (float)NROWS;
  const float mu  = stats[o] * invN;
  const float var = stats[TRD + o] * invN - mu * mu;
  const float inv = 1.0f / sqrtf(var + EPSV);
  const float g = gamma[o] * inv;
  const float bterm = beta[o] - mu * g;
  __shared__ float red[NCLS][TRD];
#pragma unroll
  for (int c = 0; c < NCLS; ++c) {
    const float wc = Wc[c * TRD + o];
    Weff[c * TRD + o] = wc * g;
    red[c][o] = wc * bterm;
  }
  __syncthreads();
  for (int s = 128; s > 0; s >>= 1) {
    if (o < s) {
#pragma unroll
      for (int c = 0; c < NCLS; ++c) red[c][o] += red[c][o + s];
    }
    __syncthreads();
  }
  if (o < NCLS) beff[o] = bc[o] + red[o][0];
}

// ---------------------------------------------------------------------------
// Kernel 4: out[row][c] = vals[row] . Weff[c] + beff[c]   (wave per row)
// ---------------------------------------------------------------------------
__global__ __launch_bounds__(256) void out_kernel(
    const float* __restrict__ vals,
    const float* __restrict__ Weff, const float* __restrict__ beff,
    float* __restrict__ out) {
  __shared__ float sW[NCLS][TRD];
  __shared__ float sb[NCLS];
  const int tid = threadIdx.x;
  for (int idx = tid; idx < NCLS * TRD; idx += 256)
    sW[idx >> 8][idx & 255] = Weff[idx];
  if (tid < NCLS) sb[tid] = beff[tid];
  __syncthreads();
  const int lane = tid & 63;
  const int row = blockIdx.x * 4 + (tid >> 6);   // 512 blocks x 4 rows
  float v[TRD / 64];
#pragma unroll
  for (int t = 0; t < TRD / 64; ++t)
    v[t] = vals[(size_t)row * TRD + lane + 64 * t];
#pragma unroll
  for (int c = 0; c < NCLS; ++c) {
    float p = 0.f;
#pragma unroll
    for (int t = 0; t < TRD / 64; ++t)
      p = fmaf(v[t], sW[c][lane + 64 * t], p);
#pragma unroll
    for (int s = 1; s < 64; s <<= 1) p += __shfl_xor(p, s, 64);
    if (lane == 0) out[(size_t)row * NCLS + c] = p + sb[c];
  }
}

// ---------------------------------------------------------------------------
extern "C" void kernel_launch(void* const* d_in, const int* in_sizes, int n_in,
                              void* d_out, int out_size, void* d_ws, size_t ws_size,
                              hipStream_t stream) {
  (void)in_sizes; (void)n_in; (void)out_size; (void)ws_size;
  const float* nodes = (const float*)d_in[0];
  const float* edges = (const float*)d_in[1];
  const float* dist  = (const float*)d_in[2];
  const int*   mask  = (const int*)d_in[3];
  const float* Wq  = (const float*)d_in[4];
  const float* bq  = (const float*)d_in[5];
  const float* Wk  = (const float*)d_in[6];
  const float* bk  = (const float*)d_in[7];
  const float* Wnv = (const float*)d_in[8];
  const float* bnv = (const float*)d_in[9];
  const float* Wev = (const float*)d_in[10];
  const float* bev = (const float*)d_in[11];
  const float* Wt  = (const float*)d_in[12];
  const float* bt  = (const float*)d_in[13];
  const float* gamma = (const float*)d_in[14];
  const float* beta  = (const float*)d_in[15];
  const float* Wc  = (const float*)d_in[16];
  const float* bc  = (const float*)d_in[17];

  float* ws    = (float*)d_ws;
  float* Q     = ws;                               // 2048*128
  float* K     = Q  + (size_t)NROWS * QKD;         // 2048*128
  float* NV    = K  + (size_t)NROWS * QKD;         // 2048*128
  float* vals  = NV + (size_t)NROWS * NVD;         // 2048*256
  float* stats = vals + (size_t)NROWS * TRD;       // 512 (sum | sqsum)
  float* Weff  = stats + 2 * TRD;                  // 5*256
  float* beff  = Weff + NCLS * TRD;                // 5
  float* outp  = (float*)d_out;

  qkv_kernel<<<NROWS, 128, 0, stream>>>(nodes, Wq, bq, Wk, bk, Wnv, bnv, Q, K, NV, stats);
  attn_kernel<<<NROWS / TI, 512, 0, stream>>>(Q, K, NV, edges, dist, mask,
                                              Wev, bev, Wt, bt, vals, stats);
  bnprep_kernel<<<1, TRD, 0, stream>>>(stats, gamma, beta, Wc, bc, Weff, beff);
  out_kernel<<<NROWS / 4, 256, 0, stream>>>(vals, Weff, beff, outp);
}